// Round 8
// baseline (435.817 us; speedup 1.0000x reference)
//
#include <hip/hip_runtime.h>

typedef unsigned short u16;
typedef __attribute__((ext_vector_type(8))) short    s16x8;
typedef __attribute__((ext_vector_type(8))) unsigned short u16x8;
typedef __attribute__((ext_vector_type(4))) float    f32x4;

typedef __attribute__((address_space(1))) const void gvoid_c;
typedef __attribute__((address_space(3))) void       lvoid;

__device__ __forceinline__ float b2f(u16 x) {
    return __builtin_bit_cast(float, (unsigned)x << 16);
}
__device__ __forceinline__ u16 f2bf(float f) {
    unsigned u = __builtin_bit_cast(unsigned, f);
    return (u16)((u + 0x7FFFu + ((u >> 16) & 1u)) >> 16);
}
__device__ __forceinline__ u16 f2bf_trunc(float f) {      // P in [0,1]: trunc ok
    return (u16)(__builtin_bit_cast(unsigned, f) >> 16);
}
__device__ __forceinline__ void gld16(const void* g, void* l) {
    __builtin_amdgcn_global_load_lds((gvoid_c*)g, (lvoid*)l, 16, 0, 0);
}

// ---------- fused weight transposes + bias concat: one launch ----------
__global__ __launch_bounds__(256) void transpose_all(
    const float* __restrict__ Wq, const float* __restrict__ Wk,
    const float* __restrict__ Wv, const float* __restrict__ Wo,
    const float* __restrict__ W1, const float* __restrict__ W2,
    const float* __restrict__ bq, const float* __restrict__ bk,
    const float* __restrict__ bv,
    u16* __restrict__ Wqkv_t, u16* __restrict__ Wo_t,
    u16* __restrict__ W1_t, u16* __restrict__ W2_t, float* __restrict__ bqkv)
{
    __shared__ u16 tile[32][33];
    int id = blockIdx.x;
    if (id >= 12288) {  // bias concat [bq|bk|bv], 12 blocks
        int i = (id - 12288) * 256 + threadIdx.x;  // 0..3071
        bqkv[i] = (i < 1024) ? bq[i] : (i < 2048 ? bk[i - 1024] : bv[i - 2048]);
        return;
    }
    const float* src; u16* dst; int R, C, bx, by;
    if (id < 4096) {
        int m = id >> 10, r = id & 1023;
        bx = r & 31; by = r >> 5; R = 1024; C = 1024;
        src = (m == 0) ? Wq : (m == 1) ? Wk : (m == 2) ? Wv : Wo;
        dst = (m == 0) ? Wqkv_t : (m == 1) ? Wqkv_t + 1024 * 1024
            : (m == 2) ? Wqkv_t + 2048 * 1024 : Wo_t;
    } else if (id < 8192) {
        int r = id - 4096; bx = r & 127; by = r >> 7; R = 1024; C = 4096;
        src = W1; dst = W1_t;
    } else {
        int r = id - 8192; bx = r & 31; by = r >> 5; R = 4096; C = 1024;
        src = W2; dst = W2_t;
    }
    int tx = threadIdx.x & 31, ty = threadIdx.x >> 5;  // 32 x 8
    int c0 = bx * 32, r0 = by * 32;
#pragma unroll
    for (int i = 0; i < 32; i += 8)
        tile[ty + i][tx] = f2bf(src[(size_t)(r0 + ty + i) * C + c0 + tx]);
    __syncthreads();
#pragma unroll
    for (int i = 0; i < 32; i += 8)
        dst[(size_t)(c0 + ty + i) * R + r0 + tx] = tile[tx][ty + i];
}

// ---------- LayerNorm: wave per row, D=1024; f32 in, bf16 out ----------
__global__ __launch_bounds__(256) void ln_k(
    const float* __restrict__ in, const float* __restrict__ gg,
    const float* __restrict__ bb, u16* __restrict__ out)
{
    const int D = 1024;
    int row  = blockIdx.x * 4 + (threadIdx.x >> 6);
    int lane = threadIdx.x & 63;
    const float* ip = in + (size_t)row * D;
    float v[16];
#pragma unroll
    for (int cc = 0; cc < 4; cc++) {
        f32x4 t = *(const f32x4*)(ip + cc * 256 + lane * 4);
#pragma unroll
        for (int i = 0; i < 4; i++) v[cc * 4 + i] = t[i];
    }
    float s1 = 0.f, s2 = 0.f;
#pragma unroll
    for (int i = 0; i < 16; i++) { s1 += v[i]; s2 += v[i] * v[i]; }
#pragma unroll
    for (int m = 1; m < 64; m <<= 1) { s1 += __shfl_xor(s1, m); s2 += __shfl_xor(s2, m); }
    float mu   = s1 * (1.f / 1024.f);
    float var  = s2 * (1.f / 1024.f) - mu * mu;
    float rstd = rsqrtf(var + 1e-5f);
#pragma unroll
    for (int cc = 0; cc < 4; cc++) {
        int e = cc * 256 + lane * 4;
        f32x4 gv = *(const f32x4*)(gg + e);
        f32x4 bv = *(const f32x4*)(bb + e);
        u16 o[4];
#pragma unroll
        for (int i = 0; i < 4; i++)
            o[i] = f2bf((v[cc * 4 + i] - mu) * rstd * gv[i] + bv[i]);
        *(__attribute__((ext_vector_type(4))) unsigned short*)(out + (size_t)row * D + e) =
            (__attribute__((ext_vector_type(4))) unsigned short){o[0], o[1], o[2], o[3]};
    }
}

// ---------- GEMM 128xBN, BK=32, 2-phase dbuf + XCD swizzle ----------
template <int BN, int RES, bool RELU, bool OUTF32>
__global__ __launch_bounds__(256) void gemm2(
    const u16* __restrict__ A, const u16* __restrict__ Bt,
    const float* __restrict__ bias, const float* __restrict__ res,
    void* __restrict__ out, int M, int N, int K)
{
    constexpr int NFR = BN / 32;
    __shared__ u16 As[2][4096];
    __shared__ u16 Bs[2][BN * 32];
    int tid = threadIdx.x, wave = tid >> 6, lane = tid & 63;
    int g = lane >> 4, c = lane & 15;
    int wm = wave >> 1, wn = wave & 1;

    int gx = gridDim.x, nwg = gx * gridDim.y;
    int id = blockIdx.y * gx + blockIdx.x;
    int swz = (id & 7) * (nwg >> 3) + (id >> 3);
    int m0 = (swz / gx) * 128, n0 = (swz % gx) * BN;

    f32x4 acc[4][NFR];
#pragma unroll
    for (int m = 0; m < 4; m++)
#pragma unroll
        for (int n = 0; n < NFR; n++) acc[m][n] = (f32x4){0, 0, 0, 0};

    int ch0 = wave * 128 + lane, ch1 = ch0 + 64;
    const u16* Ag0 = A + (size_t)(m0 + (ch0 >> 2)) * K + (ch0 & 3) * 8;
    const u16* Ag1 = A + (size_t)(m0 + (ch1 >> 2)) * K + (ch1 & 3) * 8;
    const u16* Bg0;
    const u16* Bg1 = nullptr;
    if constexpr (BN == 128) {
        Bg0 = Bt + (size_t)(n0 + (ch0 >> 2)) * K + (ch0 & 3) * 8;
        Bg1 = Bt + (size_t)(n0 + (ch1 >> 2)) * K + (ch1 & 3) * 8;
    } else {
        int chb = wave * 64 + lane;
        Bg0 = Bt + (size_t)(n0 + (chb >> 2)) * K + (chb & 3) * 8;
    }

    auto stage = [&](int buf, int kk) {
        gld16(Ag0 + kk, &As[buf][wave * 1024]);
        gld16(Ag1 + kk, &As[buf][wave * 1024 + 512]);
        if constexpr (BN == 128) {
            gld16(Bg0 + kk, &Bs[buf][wave * 1024]);
            gld16(Bg1 + kk, &Bs[buf][wave * 1024 + 512]);
        } else {
            gld16(Bg0 + kk, &Bs[buf][wave * 512]);
        }
    };

    int nt = K / 32;
    stage(0, 0);
    __syncthreads();
    int cur = 0;
    for (int t = 0; t < nt; t++) {
        if (t + 1 < nt) stage(cur ^ 1, (t + 1) * 32);
        s16x8 af[4], bfr[NFR];
#pragma unroll
        for (int m = 0; m < 4; m++)
            af[m] = *(const s16x8*)&As[cur][(wm * 64 + m * 16 + c) * 32 + g * 8];
#pragma unroll
        for (int n = 0; n < NFR; n++)
            bfr[n] = *(const s16x8*)&Bs[cur][(wn * (BN / 2) + n * 16 + c) * 32 + g * 8];
        __builtin_amdgcn_s_setprio(1);
#pragma unroll
        for (int m = 0; m < 4; m++)
#pragma unroll
            for (int n = 0; n < NFR; n++)
                acc[m][n] = __builtin_amdgcn_mfma_f32_16x16x32_bf16(af[m], bfr[n], acc[m][n], 0, 0, 0);
        __builtin_amdgcn_s_setprio(0);
        __syncthreads();
        cur ^= 1;
    }

#pragma unroll
    for (int n = 0; n < NFR; n++) {
        int col = n0 + wn * (BN / 2) + n * 16 + c;
        float bb = bias[col];
#pragma unroll
        for (int m = 0; m < 4; m++) {
#pragma unroll
            for (int j = 0; j < 4; j++) {
                int row = m0 + wm * 64 + m * 16 + g * 4 + j;
                float v = acc[m][n][j] + bb;
                if constexpr (RES == 2) v += res[(size_t)row * N + col];
                if constexpr (RELU) v = fmaxf(v, 0.f);
                if constexpr (OUTF32) ((float*)out)[(size_t)row * N + col] = v;
                else                  ((u16*)out)[(size_t)row * N + col] = f2bf(v);
            }
        }
    }
}

// ---------- GEMM 128x64, BK=64: swizzled LDS, 16 MFMA per barrier ----------
// out f32 = A @ Bt^T + bias + res (FFN2 / Wo shape: N=1024)
__global__ __launch_bounds__(256) void gemm_n64_k64(
    const u16* __restrict__ A, const u16* __restrict__ Bt,
    const float* __restrict__ bias, const float* __restrict__ res,
    float* __restrict__ out, int M, int N, int K)
{
    __shared__ u16 As[2][8192];   // [128][64] col8-XOR-swizzled
    __shared__ u16 Bs[2][4096];   // [64][64]
    int tid = threadIdx.x, wave = tid >> 6, lane = tid & 63;
    int g = lane >> 4, c = lane & 15;
    int wm = wave >> 1, wn = wave & 1;

    int gx = gridDim.x, nwg = gx * gridDim.y;
    int id = blockIdx.y * gx + blockIdx.x;
    int swz = (id & 7) * (nwg >> 3) + (id >> 3);
    int m0 = (swz / gx) * 128, n0 = (swz % gx) * 64;

    f32x4 acc[4][2];
#pragma unroll
    for (int m = 0; m < 4; m++)
#pragma unroll
        for (int n = 0; n < 2; n++) acc[m][n] = (f32x4){0, 0, 0, 0};

    // staging sources (pre-swizzled col so LDS-linear dest yields swizzled tile)
    const u16* asrc[4];
#pragma unroll
    for (int k = 0; k < 4; k++) {
        int ch = k * 256 + tid, row = ch >> 3, c8 = ch & 7;
        asrc[k] = A + (size_t)(m0 + row) * K + ((c8 ^ (row & 7)) * 8);
    }
    const u16* bsrc[2];
#pragma unroll
    for (int k = 0; k < 2; k++) {
        int ch = k * 256 + tid, row = ch >> 3, c8 = ch & 7;
        bsrc[k] = Bt + (size_t)(n0 + row) * K + ((c8 ^ (row & 7)) * 8);
    }

    auto stage = [&](int buf, int k0) {
#pragma unroll
        for (int k = 0; k < 4; k++)
            gld16(asrc[k] + k0, &As[buf][(k * 256 + wave * 64) * 8]);
#pragma unroll
        for (int k = 0; k < 2; k++)
            gld16(bsrc[k] + k0, &Bs[buf][(k * 256 + wave * 64) * 8]);
    };

    int nt = K / 64;
    stage(0, 0);
    __syncthreads();
    int cur = 0;
    int x7 = c & 7;
    for (int t = 0; t < nt; t++) {
        if (t + 1 < nt) stage(cur ^ 1, (t + 1) * 64);
        s16x8 af[2][4], bfr[2][2];
#pragma unroll
        for (int kk = 0; kk < 2; kk++) {
#pragma unroll
            for (int m = 0; m < 4; m++)
                af[kk][m] = *(const s16x8*)&As[cur][(wm * 64 + m * 16 + c) * 64 + ((kk * 4 + g) ^ x7) * 8];
#pragma unroll
            for (int n = 0; n < 2; n++)
                bfr[kk][n] = *(const s16x8*)&Bs[cur][(wn * 32 + n * 16 + c) * 64 + ((kk * 4 + g) ^ x7) * 8];
        }
        __builtin_amdgcn_s_setprio(1);
#pragma unroll
        for (int kk = 0; kk < 2; kk++)
#pragma unroll
            for (int m = 0; m < 4; m++)
#pragma unroll
                for (int n = 0; n < 2; n++)
                    acc[m][n] = __builtin_amdgcn_mfma_f32_16x16x32_bf16(af[kk][m], bfr[kk][n], acc[m][n], 0, 0, 0);
        __builtin_amdgcn_s_setprio(0);
        __syncthreads();
        cur ^= 1;
    }

#pragma unroll
    for (int n = 0; n < 2; n++) {
        int col = n0 + wn * 32 + n * 16 + c;
        float bb = bias[col];
#pragma unroll
        for (int m = 0; m < 4; m++) {
#pragma unroll
            for (int j = 0; j < 4; j++) {
                int row = m0 + wm * 64 + m * 16 + g * 4 + j;
                out[(size_t)row * N + col] = acc[m][n][j] + bb + res[(size_t)row * N + col];
            }
        }
    }
}

// ---------- V transpose: qkv V-cols -> vt[bh][d][s], XOR-swizzled per 64-kv tile ----------
__global__ __launch_bounds__(256) void v_transpose(
    const u16* __restrict__ qkv, u16* __restrict__ vt)
{
    const int S = 2048, NC = 3072;
    __shared__ u16 tile[64][72];
    int st = blockIdx.x, bh = blockIdx.y, b = bh >> 4, h = bh & 15;
    int tid = threadIdx.x;
    int i = tid >> 3, cb8 = (tid & 7) * 8;
    const u16* src = qkv + (size_t)(b * S + st * 64) * NC + 2048 + h * 64;
    u16x8 a0 = *(const u16x8*)(src + (size_t)i * NC + cb8);
    u16x8 a1 = *(const u16x8*)(src + (size_t)(i + 32) * NC + cb8);
    *(u16x8*)&tile[i][cb8]      = a0;
    *(u16x8*)&tile[i + 32][cb8] = a1;
    __syncthreads();
    int d = tid >> 3, e8 = (tid & 7) * 8;
    int m = (d & 7) * 8;
#pragma unroll
    for (int rr = 0; rr < 2; rr++) {
        int r = d + rr * 32;
        u16x8 o;
#pragma unroll
        for (int j = 0; j < 8; j++) o[j] = tile[(e8 ^ m) + j][r];
        *(u16x8*)(vt + ((size_t)bh * 64 + r) * 2048 + st * 64 + e8) = o;
    }
}

// ---------- flash attention v5: one q-tile/block (LPT order), 40KB LDS, defer-max ----------
__global__ __launch_bounds__(256) void attn_fwd5(
    const u16* __restrict__ qkv, const u16* __restrict__ vt,
    u16* __restrict__ o)
{
    const int S = 2048, NC = 3072;
    __shared__ u16 Ks[2][4096];       // [64][64] swizzled
    __shared__ u16 Vs[2][4096];       // [64][64] swizzled (V^T)
    __shared__ u16 Plds[4][16][64];   // XOR-swizzled (elem ^ ((row&7)<<3)); total LDS = 40960
    int qt = 31 - blockIdx.x;         // LPT: longest blocks dispatch first
    int bh = blockIdx.y, b = bh >> 4, h = bh & 15;
    int tid = threadIdx.x, wave = tid >> 6, lane = tid & 63;
    int g = lane >> 4, c = lane & 15;
    int sr = tid >> 3, scb8 = (tid & 7) * 8;
    int mS = (sr & 7) * 8;            // K/V staging XOR mask
    int mR = (c & 7) * 8;             // K/V read XOR mask
    int pW = ((g * 4) & 7) << 3;      // P write XOR base (row = g*4+j)
    int pR = (c & 7) << 3;            // P read XOR mask (row = c)

    const u16* kbase = qkv + (size_t)b * S * NC + 1024 + h * 64;
    const u16* vbase = vt + (size_t)bh * 64 * 2048;

    auto stageKV = [&](int buf, int t0) {
        gld16(kbase + (size_t)(t0 + sr)      * NC + (scb8 ^ mS), &Ks[buf][wave * 512]);
        gld16(kbase + (size_t)(t0 + sr + 32) * NC + (scb8 ^ mS), &Ks[buf][2048 + wave * 512]);
        gld16(vbase + (size_t)sr        * 2048 + t0 + scb8, &Vs[buf][wave * 512]);
        gld16(vbase + (size_t)(sr + 32) * 2048 + t0 + scb8, &Vs[buf][2048 + wave * 512]);
    };

    int q0 = qt * 64 + wave * 16;
    const u16* qptr = qkv + (size_t)(b * S + q0 + c) * NC + h * 64;
    s16x8 qf0 = *(const s16x8*)(qptr + g * 8);
    s16x8 qf1 = *(const s16x8*)(qptr + 32 + g * 8);

    float mr[4], lr[4];
    f32x4 acc[4];
#pragma unroll
    for (int j = 0; j < 4; j++) { mr[j] = -1e30f; lr[j] = 0.f; }
#pragma unroll
    for (int n = 0; n < 4; n++) acc[n] = (f32x4){0, 0, 0, 0};

    auto do_tile = [&](int cur, int t0, bool masked) __attribute__((always_inline)) {
        // QK^T from LDS
        f32x4 s[4];
        __builtin_amdgcn_s_setprio(1);
#pragma unroll
        for (int kt = 0; kt < 4; kt++) {
            int r = kt * 16 + c;
            s16x8 kf0 = *(const s16x8*)&Ks[cur][r * 64 + ((g * 8) ^ mR)];
            s16x8 kf1 = *(const s16x8*)&Ks[cur][r * 64 + ((32 + g * 8) ^ mR)];
            f32x4 sv = (f32x4){0, 0, 0, 0};
            sv = __builtin_amdgcn_mfma_f32_16x16x32_bf16(qf0, kf0, sv, 0, 0, 0);
            sv = __builtin_amdgcn_mfma_f32_16x16x32_bf16(qf1, kf1, sv, 0, 0, 0);
            s[kt] = sv;
        }
        __builtin_amdgcn_s_setprio(0);
        // scale (+causal mask on diagonal tile only)
#pragma unroll
        for (int kt = 0; kt < 4; kt++) {
#pragma unroll
            for (int j = 0; j < 4; j++) {
                if (masked) {
                    int kcol = t0 + kt * 16 + c;
                    int qrow = q0 + g * 4 + j;
                    s[kt][j] = (kcol <= qrow) ? s[kt][j] * 0.125f : -1e30f;
                } else {
                    s[kt][j] *= 0.125f;
                }
            }
        }
        // tile row-max (16-lane groups)
        float tm4[4];
#pragma unroll
        for (int j = 0; j < 4; j++) {
            float tm = fmaxf(fmaxf(s[0][j], s[1][j]), fmaxf(s[2][j], s[3][j]));
#pragma unroll
            for (int m = 1; m < 16; m <<= 1) tm = fmaxf(tm, __shfl_xor(tm, m));
            tm4[j] = tm;
        }
        // defer-max: rescale only if some row's max grew (bit-identical; wave-uniform branch)
        bool grow = (tm4[0] > mr[0]) | (tm4[1] > mr[1]) | (tm4[2] > mr[2]) | (tm4[3] > mr[3]);
        if (__any(grow)) {
#pragma unroll
            for (int j = 0; j < 4; j++) {
                float mnew = fmaxf(mr[j], tm4[j]);
                float corr = __expf(mr[j] - mnew);
                mr[j] = mnew;
                lr[j] *= corr;
#pragma unroll
                for (int n = 0; n < 4; n++) acc[n][j] *= corr;
            }
        }
        // exp + row-sum
#pragma unroll
        for (int j = 0; j < 4; j++) {
            float rs = 0.f;
#pragma unroll
            for (int kt = 0; kt < 4; kt++) { float p = __expf(s[kt][j] - mr[j]); s[kt][j] = p; rs += p; }
#pragma unroll
            for (int m = 1; m < 16; m <<= 1) rs += __shfl_xor(rs, m);
            lr[j] += rs;
        }
        // P -> LDS (bf16 trunc, wave-local, XOR-swizzled stride-64)
#pragma unroll
        for (int kt = 0; kt < 4; kt++)
#pragma unroll
            for (int j = 0; j < 4; j++)
                Plds[wave][g * 4 + j][(kt * 16 + c) ^ (pW ^ ((j & 7) << 3) ? ((g * 4 + j) & 7) << 3 : ((g * 4 + j) & 7) << 3)] = f2bf_trunc(s[kt][j]);
        // PV
        s16x8 pa0 = *(const s16x8*)&Plds[wave][c][(g * 8) ^ pR];
        s16x8 pa1 = *(const s16x8*)&Plds[wave][c][(32 + g * 8) ^ pR];
        __builtin_amdgcn_s_setprio(1);
#pragma unroll
        for (int n = 0; n < 4; n++) {
            int r = n * 16 + c;
            s16x8 vb0 = *(const s16x8*)&Vs[cur][r * 64 + ((g * 8) ^ mR)];
            s16x8 vb1 = *(const s16x8*)&Vs[cur][r * 64 + ((32 + g * 8) ^ mR)];
            acc[n] = __builtin_amdgcn_mfma_f32_16x16x32_bf16(pa0, vb0, acc[n], 0, 0, 0);
            acc[n] = __builtin_amdgcn_mfma_f32_16x16x32_bf16(pa1, vb1, acc[n], 0, 0, 0);
        }
        __builtin_amdgcn_s_setprio(0);
    };

    stageKV(0, 0);
    __syncthreads();              // prologue staged
    int cur = 0;
    for (int t = 0; t < qt; t++) {                 // strictly-below-diagonal tiles
        stageKV(cur ^ 1, (t + 1) * 64);            // prefetch next tile
        do_tile(cur, t * 64, false);
        __syncthreads();
        cur ^= 1;
    }
    do_tile(cur, qt * 64, true);                   // diagonal tile (masked)

    // epilogue: normalize and store bf16
#pragma unroll
    for (int j = 0; j < 4; j++) {
        float inv = 1.f / lr[j];
        size_t rbase = (size_t)(b * S + q0 + g * 4 + j) * 1024 + h * 64;
#pragma unroll
        for (int n = 0; n < 4; n++)
            o[rbase + n * 16 + c] = f2bf(acc[n][j] * inv);
    }
}

// ---------- host ----------
extern "C" void kernel_launch(void* const* d_in, const int* in_sizes, int n_in,
                              void* d_out, int out_size, void* d_ws, size_t ws_size,
                              hipStream_t stream)
{
    const float* x    = (const float*)d_in[0];
    const float* Wq   = (const float*)d_in[2];  const float* bq = (const float*)d_in[3];
    const float* Wk   = (const float*)d_in[4];  const float* bk = (const float*)d_in[5];
    const float* Wv   = (const float*)d_in[6];  const float* bv = (const float*)d_in[7];
    const float* Wo   = (const float*)d_in[8];  const float* bo = (const float*)d_in[9];
    const float* W1   = (const float*)d_in[10]; const float* b1 = (const float*)d_in[11];
    const float* W2   = (const float*)d_in[12]; const float* b2 = (const float*)d_in[13];
    const float* ln1g = (const float*)d_in[14]; const float* ln1b = (const float*)d_in[15];
    const float* ln2g = (const float*)d_in[16]; const float* ln2b = (const float*)d_in[17];

    unsigned char* ws = (unsigned char*)d_ws;
    u16*   Wqkv_t = (u16*)(ws + 0);              //  6,291,456  bf16 [3072][1024]
    u16*   Wo_t   = (u16*)(ws + 6291456);        //  2,097,152  bf16 [1024][1024]
    u16*   W1_t   = (u16*)(ws + 8388608);        //  8,388,608  bf16 [4096][1024]
    u16*   W2_t   = (u16*)(ws + 16777216);       //  8,388,608  bf16 [1024][4096]
    float* bqkv   = (float*)(ws + 25165824);     //     12,288  f32  [3072]
    u16*   lnbuf  = (u16*)(ws + 25178112);       //  8,388,608  bf16
    u16*   qkvbuf = (u16*)(ws + 33566720);       // 25,165,824  bf16 [4096][3072]
    u16*   attnb  = (u16*)(ws + 58732544);       //  8,388,608  bf16 [4096][1024]
    u16*   f1buf  = (u16*)(ws + 33566720);       // 33,554,432  bf16 [4096][4096] (aliases qkv+attn)
    float* hbuf   = (float*)(ws + 67121152);     // 16,777,216  f32  [4096][1024]
    u16*   vtbuf  = (u16*)(ws + 67121152);       //  8,388,608  bf16 [32][64][2048] (aliases hbuf)

    transpose_all<<<12300, 256, 0, stream>>>(Wq, Wk, Wv, Wo, W1, W2, bq, bk, bv,
                                             Wqkv_t, Wo_t, W1_t, W2_t, bqkv);

    // ln1 -> fused QKV GEMM -> V transpose -> attention
    ln_k<<<1024, 256, 0, stream>>>(x, ln1g, ln1b, lnbuf);
    gemm2<128, 0, false, false><<<dim3(24, 32), 256, 0, stream>>>(
        lnbuf, Wqkv_t, bqkv, nullptr, qkvbuf, 4096, 3072, 1024);
    v_transpose<<<dim3(32, 32), 256, 0, stream>>>(qkvbuf, vtbuf);
    attn_fwd5<<<dim3(32, 32), 256, 0, stream>>>(qkvbuf, vtbuf, attnb);

    // h = x + attn @ Wo + bo  (f32)
    gemm_n64_k64<<<dim3(16, 32), 256, 0, stream>>>(
        attnb, Wo_t, bo, x, hbuf, 4096, 1024, 1024);

    // ln2 -> FFN1 (relu) -> FFN2 (+h residual) -> out (f32)
    ln_k<<<1024, 256, 0, stream>>>(hbuf, ln2g, ln2b, lnbuf);
    gemm2<128, 0, true, false><<<dim3(32, 32), 256, 0, stream>>>(
        lnbuf, W1_t, b1, nullptr, f1buf, 4096, 4096, 1024);
    gemm_n64_k64<<<dim3(16, 32), 256, 0, stream>>>(
        f1buf, W2_t, b2, hbuf, (float*)d_out, 4096, 1024, 4096);
}

// Round 10
// 374.110 us; speedup vs baseline: 1.1649x; 1.1649x over previous
//
#include <hip/hip_runtime.h>

typedef unsigned short u16;
typedef __attribute__((ext_vector_type(8))) short    s16x8;
typedef __attribute__((ext_vector_type(8))) unsigned short u16x8;
typedef __attribute__((ext_vector_type(4))) float    f32x4;

typedef __attribute__((address_space(1))) const void gvoid_c;
typedef __attribute__((address_space(3))) void       lvoid;

__device__ __forceinline__ float b2f(u16 x) {
    return __builtin_bit_cast(float, (unsigned)x << 16);
}
__device__ __forceinline__ u16 f2bf(float f) {
    unsigned u = __builtin_bit_cast(unsigned, f);
    return (u16)((u + 0x7FFFu + ((u >> 16) & 1u)) >> 16);
}
__device__ __forceinline__ u16 f2bf_trunc(float f) {      // P in [0,1]: trunc ok
    return (u16)(__builtin_bit_cast(unsigned, f) >> 16);
}
__device__ __forceinline__ void gld16(const void* g, void* l) {
    __builtin_amdgcn_global_load_lds((gvoid_c*)g, (lvoid*)l, 16, 0, 0);
}
__device__ __forceinline__ float fexp2(float x) {         // native 2^x (gfx9 hw-interlocked)
    float r; asm("v_exp_f32 %0, %1" : "=v"(r) : "v"(x)); return r;
}
// 16-lane (DPP-row) allreduce: quad xor1, xor2, then row_ror 4, 8. Pure VALU.
__device__ __forceinline__ float dpp_max16(float x) {
    int v = __builtin_bit_cast(int, x);
    x = fmaxf(x, __builtin_bit_cast(float, __builtin_amdgcn_mov_dpp(v, 0xB1, 0xF, 0xF, true)));
    v = __builtin_bit_cast(int, x);
    x = fmaxf(x, __builtin_bit_cast(float, __builtin_amdgcn_mov_dpp(v, 0x4E, 0xF, 0xF, true)));
    v = __builtin_bit_cast(int, x);
    x = fmaxf(x, __builtin_bit_cast(float, __builtin_amdgcn_mov_dpp(v, 0x124, 0xF, 0xF, true)));
    v = __builtin_bit_cast(int, x);
    x = fmaxf(x, __builtin_bit_cast(float, __builtin_amdgcn_mov_dpp(v, 0x128, 0xF, 0xF, true)));
    return x;
}
__device__ __forceinline__ float dpp_sum16(float x) {
    int v = __builtin_bit_cast(int, x);
    x = x + __builtin_bit_cast(float, __builtin_amdgcn_mov_dpp(v, 0xB1, 0xF, 0xF, true));
    v = __builtin_bit_cast(int, x);
    x = x + __builtin_bit_cast(float, __builtin_amdgcn_mov_dpp(v, 0x4E, 0xF, 0xF, true));
    v = __builtin_bit_cast(int, x);
    x = x + __builtin_bit_cast(float, __builtin_amdgcn_mov_dpp(v, 0x124, 0xF, 0xF, true));
    v = __builtin_bit_cast(int, x);
    x = x + __builtin_bit_cast(float, __builtin_amdgcn_mov_dpp(v, 0x128, 0xF, 0xF, true));
    return x;
}

// ---------- fused weight transposes + bias concat: one launch ----------
__global__ __launch_bounds__(256) void transpose_all(
    const float* __restrict__ Wq, const float* __restrict__ Wk,
    const float* __restrict__ Wv, const float* __restrict__ Wo,
    const float* __restrict__ W1, const float* __restrict__ W2,
    const float* __restrict__ bq, const float* __restrict__ bk,
    const float* __restrict__ bv,
    u16* __restrict__ Wqkv_t, u16* __restrict__ Wo_t,
    u16* __restrict__ W1_t, u16* __restrict__ W2_t, float* __restrict__ bqkv)
{
    __shared__ u16 tile[32][33];
    int id = blockIdx.x;
    if (id >= 12288) {  // bias concat [bq|bk|bv], 12 blocks
        int i = (id - 12288) * 256 + threadIdx.x;  // 0..3071
        bqkv[i] = (i < 1024) ? bq[i] : (i < 2048 ? bk[i - 1024] : bv[i - 2048]);
        return;
    }
    const float* src; u16* dst; int R, C, bx, by;
    if (id < 4096) {
        int m = id >> 10, r = id & 1023;
        bx = r & 31; by = r >> 5; R = 1024; C = 1024;
        src = (m == 0) ? Wq : (m == 1) ? Wk : (m == 2) ? Wv : Wo;
        dst = (m == 0) ? Wqkv_t : (m == 1) ? Wqkv_t + 1024 * 1024
            : (m == 2) ? Wqkv_t + 2048 * 1024 : Wo_t;
    } else if (id < 8192) {
        int r = id - 4096; bx = r & 127; by = r >> 7; R = 1024; C = 4096;
        src = W1; dst = W1_t;
    } else {
        int r = id - 8192; bx = r & 31; by = r >> 5; R = 4096; C = 1024;
        src = W2; dst = W2_t;
    }
    int tx = threadIdx.x & 31, ty = threadIdx.x >> 5;  // 32 x 8
    int c0 = bx * 32, r0 = by * 32;
#pragma unroll
    for (int i = 0; i < 32; i += 8)
        tile[ty + i][tx] = f2bf(src[(size_t)(r0 + ty + i) * C + c0 + tx]);
    __syncthreads();
#pragma unroll
    for (int i = 0; i < 32; i += 8)
        dst[(size_t)(c0 + ty + i) * R + r0 + tx] = tile[tx][ty + i];
}

// ---------- LayerNorm: wave per row, D=1024; f32 in, bf16 out ----------
__global__ __launch_bounds__(256) void ln_k(
    const float* __restrict__ in, const float* __restrict__ gg,
    const float* __restrict__ bb, u16* __restrict__ out)
{
    const int D = 1024;
    int row  = blockIdx.x * 4 + (threadIdx.x >> 6);
    int lane = threadIdx.x & 63;
    const float* ip = in + (size_t)row * D;
    float v[16];
#pragma unroll
    for (int cc = 0; cc < 4; cc++) {
        f32x4 t = *(const f32x4*)(ip + cc * 256 + lane * 4);
#pragma unroll
        for (int i = 0; i < 4; i++) v[cc * 4 + i] = t[i];
    }
    float s1 = 0.f, s2 = 0.f;
#pragma unroll
    for (int i = 0; i < 16; i++) { s1 += v[i]; s2 += v[i] * v[i]; }
#pragma unroll
    for (int m = 1; m < 64; m <<= 1) { s1 += __shfl_xor(s1, m); s2 += __shfl_xor(s2, m); }
    float mu   = s1 * (1.f / 1024.f);
    float var  = s2 * (1.f / 1024.f) - mu * mu;
    float rstd = rsqrtf(var + 1e-5f);
#pragma unroll
    for (int cc = 0; cc < 4; cc++) {
        int e = cc * 256 + lane * 4;
        f32x4 gv = *(const f32x4*)(gg + e);
        f32x4 bv = *(const f32x4*)(bb + e);
        u16 o[4];
#pragma unroll
        for (int i = 0; i < 4; i++)
            o[i] = f2bf((v[cc * 4 + i] - mu) * rstd * gv[i] + bv[i]);
        *(__attribute__((ext_vector_type(4))) unsigned short*)(out + (size_t)row * D + e) =
            (__attribute__((ext_vector_type(4))) unsigned short){o[0], o[1], o[2], o[3]};
    }
}

// ---------- GEMM 128xBN, BK=32, 2-phase dbuf + XCD swizzle ----------
// QSC: scale cols<1024 by 0.125*log2e (Q pre-scale for exp2-domain softmax)
template <int BN, int RES, bool RELU, bool OUTF32, int QSC = 0>
__global__ __launch_bounds__(256) void gemm2(
    const u16* __restrict__ A, const u16* __restrict__ Bt,
    const float* __restrict__ bias, const float* __restrict__ res,
    void* __restrict__ out, int M, int N, int K)
{
    constexpr int NFR = BN / 32;
    __shared__ u16 As[2][4096];
    __shared__ u16 Bs[2][BN * 32];
    int tid = threadIdx.x, wave = tid >> 6, lane = tid & 63;
    int g = lane >> 4, c = lane & 15;
    int wm = wave >> 1, wn = wave & 1;

    int gx = gridDim.x, nwg = gx * gridDim.y;
    int id = blockIdx.y * gx + blockIdx.x;
    int swz = (id & 7) * (nwg >> 3) + (id >> 3);
    int m0 = (swz / gx) * 128, n0 = (swz % gx) * BN;

    f32x4 acc[4][NFR];
#pragma unroll
    for (int m = 0; m < 4; m++)
#pragma unroll
        for (int n = 0; n < NFR; n++) acc[m][n] = (f32x4){0, 0, 0, 0};

    int ch0 = wave * 128 + lane, ch1 = ch0 + 64;
    const u16* Ag0 = A + (size_t)(m0 + (ch0 >> 2)) * K + (ch0 & 3) * 8;
    const u16* Ag1 = A + (size_t)(m0 + (ch1 >> 2)) * K + (ch1 & 3) * 8;
    const u16* Bg0;
    const u16* Bg1 = nullptr;
    if constexpr (BN == 128) {
        Bg0 = Bt + (size_t)(n0 + (ch0 >> 2)) * K + (ch0 & 3) * 8;
        Bg1 = Bt + (size_t)(n0 + (ch1 >> 2)) * K + (ch1 & 3) * 8;
    } else {
        int chb = wave * 64 + lane;
        Bg0 = Bt + (size_t)(n0 + (chb >> 2)) * K + (chb & 3) * 8;
    }

    auto stage = [&](int buf, int kk) {
        gld16(Ag0 + kk, &As[buf][wave * 1024]);
        gld16(Ag1 + kk, &As[buf][wave * 1024 + 512]);
        if constexpr (BN == 128) {
            gld16(Bg0 + kk, &Bs[buf][wave * 1024]);
            gld16(Bg1 + kk, &Bs[buf][wave * 1024 + 512]);
        } else {
            gld16(Bg0 + kk, &Bs[buf][wave * 512]);
        }
    };

    int nt = K / 32;
    stage(0, 0);
    __syncthreads();
    int cur = 0;
    for (int t = 0; t < nt; t++) {
        if (t + 1 < nt) stage(cur ^ 1, (t + 1) * 32);
        s16x8 af[4], bfr[NFR];
#pragma unroll
        for (int m = 0; m < 4; m++)
            af[m] = *(const s16x8*)&As[cur][(wm * 64 + m * 16 + c) * 32 + g * 8];
#pragma unroll
        for (int n = 0; n < NFR; n++)
            bfr[n] = *(const s16x8*)&Bs[cur][(wn * (BN / 2) + n * 16 + c) * 32 + g * 8];
        __builtin_amdgcn_s_setprio(1);
#pragma unroll
        for (int m = 0; m < 4; m++)
#pragma unroll
            for (int n = 0; n < NFR; n++)
                acc[m][n] = __builtin_amdgcn_mfma_f32_16x16x32_bf16(af[m], bfr[n], acc[m][n], 0, 0, 0);
        __builtin_amdgcn_s_setprio(0);
        __syncthreads();
        cur ^= 1;
    }

#pragma unroll
    for (int n = 0; n < NFR; n++) {
        int col = n0 + wn * (BN / 2) + n * 16 + c;
        float bb = bias[col];
#pragma unroll
        for (int m = 0; m < 4; m++) {
#pragma unroll
            for (int j = 0; j < 4; j++) {
                int row = m0 + wm * 64 + m * 16 + g * 4 + j;
                float v = acc[m][n][j] + bb;
                if constexpr (QSC) { if (col < 1024) v *= 0.18033688f; }  // 0.125*log2(e)
                if constexpr (RES == 2) v += res[(size_t)row * N + col];
                if constexpr (RELU) v = fmaxf(v, 0.f);
                if constexpr (OUTF32) ((float*)out)[(size_t)row * N + col] = v;
                else                  ((u16*)out)[(size_t)row * N + col] = f2bf(v);
            }
        }
    }
}

// ---------- GEMM 128x64, BK=64: swizzled LDS, 16 MFMA per barrier ----------
__global__ __launch_bounds__(256) void gemm_n64_k64(
    const u16* __restrict__ A, const u16* __restrict__ Bt,
    const float* __restrict__ bias, const float* __restrict__ res,
    float* __restrict__ out, int M, int N, int K)
{
    __shared__ u16 As[2][8192];   // [128][64] col8-XOR-swizzled
    __shared__ u16 Bs[2][4096];   // [64][64]
    int tid = threadIdx.x, wave = tid >> 6, lane = tid & 63;
    int g = lane >> 4, c = lane & 15;
    int wm = wave >> 1, wn = wave & 1;

    int gx = gridDim.x, nwg = gx * gridDim.y;
    int id = blockIdx.y * gx + blockIdx.x;
    int swz = (id & 7) * (nwg >> 3) + (id >> 3);
    int m0 = (swz / gx) * 128, n0 = (swz % gx) * 64;

    f32x4 acc[4][2];
#pragma unroll
    for (int m = 0; m < 4; m++)
#pragma unroll
        for (int n = 0; n < 2; n++) acc[m][n] = (f32x4){0, 0, 0, 0};

    const u16* asrc[4];
#pragma unroll
    for (int k = 0; k < 4; k++) {
        int ch = k * 256 + tid, row = ch >> 3, c8 = ch & 7;
        asrc[k] = A + (size_t)(m0 + row) * K + ((c8 ^ (row & 7)) * 8);
    }
    const u16* bsrc[2];
#pragma unroll
    for (int k = 0; k < 2; k++) {
        int ch = k * 256 + tid, row = ch >> 3, c8 = ch & 7;
        bsrc[k] = Bt + (size_t)(n0 + row) * K + ((c8 ^ (row & 7)) * 8);
    }

    auto stage = [&](int buf, int k0) {
#pragma unroll
        for (int k = 0; k < 4; k++)
            gld16(asrc[k] + k0, &As[buf][(k * 256 + wave * 64) * 8]);
#pragma unroll
        for (int k = 0; k < 2; k++)
            gld16(bsrc[k] + k0, &Bs[buf][(k * 256 + wave * 64) * 8]);
    };

    int nt = K / 64;
    stage(0, 0);
    __syncthreads();
    int cur = 0;
    int x7 = c & 7;
    for (int t = 0; t < nt; t++) {
        if (t + 1 < nt) stage(cur ^ 1, (t + 1) * 64);
        s16x8 af[2][4], bfr[2][2];
#pragma unroll
        for (int kk = 0; kk < 2; kk++) {
#pragma unroll
            for (int m = 0; m < 4; m++)
                af[kk][m] = *(const s16x8*)&As[cur][(wm * 64 + m * 16 + c) * 64 + ((kk * 4 + g) ^ x7) * 8];
#pragma unroll
            for (int n = 0; n < 2; n++)
                bfr[kk][n] = *(const s16x8*)&Bs[cur][(wn * 32 + n * 16 + c) * 64 + ((kk * 4 + g) ^ x7) * 8];
        }
        __builtin_amdgcn_s_setprio(1);
#pragma unroll
        for (int kk = 0; kk < 2; kk++)
#pragma unroll
            for (int m = 0; m < 4; m++)
#pragma unroll
                for (int n = 0; n < 2; n++)
                    acc[m][n] = __builtin_amdgcn_mfma_f32_16x16x32_bf16(af[kk][m], bfr[kk][n], acc[m][n], 0, 0, 0);
        __builtin_amdgcn_s_setprio(0);
        __syncthreads();
        cur ^= 1;
    }

#pragma unroll
    for (int n = 0; n < 2; n++) {
        int col = n0 + wn * 32 + n * 16 + c;
        float bb = bias[col];
#pragma unroll
        for (int m = 0; m < 4; m++) {
#pragma unroll
            for (int j = 0; j < 4; j++) {
                int row = m0 + wm * 64 + m * 16 + g * 4 + j;
                out[(size_t)row * N + col] = acc[m][n][j] + bb + res[(size_t)row * N + col];
            }
        }
    }
}

// ---------- V transpose: qkv V-cols -> vt[bh][d][s], XOR-swizzled per 64-kv tile ----------
__global__ __launch_bounds__(256) void v_transpose(
    const u16* __restrict__ qkv, u16* __restrict__ vt)
{
    const int S = 2048, NC = 3072;
    __shared__ u16 tile[64][72];
    int st = blockIdx.x, bh = blockIdx.y, b = bh >> 4, h = bh & 15;
    int tid = threadIdx.x;
    int i = tid >> 3, cb8 = (tid & 7) * 8;
    const u16* src = qkv + (size_t)(b * S + st * 64) * NC + 2048 + h * 64;
    u16x8 a0 = *(const u16x8*)(src + (size_t)i * NC + cb8);
    u16x8 a1 = *(const u16x8*)(src + (size_t)(i + 32) * NC + cb8);
    *(u16x8*)&tile[i][cb8]      = a0;
    *(u16x8*)&tile[i + 32][cb8] = a1;
    __syncthreads();
    int d = tid >> 3, e8 = (tid & 7) * 8;
    int m = (d & 7) * 8;
#pragma unroll
    for (int rr = 0; rr < 2; rr++) {
        int r = d + rr * 32;
        u16x8 o;
#pragma unroll
        for (int j = 0; j < 8; j++) o[j] = tile[(e8 ^ m) + j][r];
        *(u16x8*)(vt + ((size_t)bh * 64 + r) * 2048 + st * 64 + e8) = o;
    }
}

// ---------- flash attention v6: paired blocks, DPP softmax, exp2 domain ----------
// Q pre-scaled by 0.125*log2e in QKV GEMM; P = 2^(s-m).
__global__ __launch_bounds__(256) void attn_fwd6(
    const u16* __restrict__ qkv, const u16* __restrict__ vt,
    u16* __restrict__ o)
{
    const int S = 2048, NC = 3072;
    __shared__ u16 Ks[2][4096];       // [64][64] swizzled
    __shared__ u16 Vs[2][4096];       // [64][64] swizzled (V^T)
    __shared__ u16 Plds[4][16][64];   // XOR-swizzled col ^ ((row&7)<<3); LDS total 40960
    int qp = blockIdx.x, bh = blockIdx.y, b = bh >> 4, h = bh & 15;
    int tid = threadIdx.x, wave = tid >> 6, lane = tid & 63;
    int g = lane >> 4, c = lane & 15;
    int sr = tid >> 3, scb8 = (tid & 7) * 8;
    int mS = (sr & 7) * 8;            // K/V staging XOR mask
    int mR = (c & 7) * 8;             // K/V read XOR mask
    int pR = (c & 7) << 3;            // P read XOR mask (row = c)

    const u16* kbase = qkv + (size_t)b * S * NC + 1024 + h * 64;
    const u16* vbase = vt + (size_t)bh * 64 * 2048;

    auto stageKV = [&](int buf, int t0) {
        gld16(kbase + (size_t)(t0 + sr)      * NC + (scb8 ^ mS), &Ks[buf][wave * 512]);
        gld16(kbase + (size_t)(t0 + sr + 32) * NC + (scb8 ^ mS), &Ks[buf][2048 + wave * 512]);
        gld16(vbase + (size_t)sr        * 2048 + t0 + scb8, &Vs[buf][wave * 512]);
        gld16(vbase + (size_t)(sr + 32) * 2048 + t0 + scb8, &Vs[buf][2048 + wave * 512]);
    };

#pragma unroll 1
    for (int ph = 0; ph < 2; ph++) {
        int qt = ph ? qp : 31 - qp;   // paired: uniform 33 tile-iters per block
        int q0 = qt * 64 + wave * 16;
        const u16* qptr = qkv + (size_t)(b * S + q0 + c) * NC + h * 64;
        s16x8 qf0 = *(const s16x8*)(qptr + g * 8);
        s16x8 qf1 = *(const s16x8*)(qptr + 32 + g * 8);

        float mr[4], lr[4];
        f32x4 acc[4];
#pragma unroll
        for (int j = 0; j < 4; j++) { mr[j] = -1e30f; lr[j] = 0.f; }
#pragma unroll
        for (int n = 0; n < 4; n++) acc[n] = (f32x4){0, 0, 0, 0};

        auto do_tile = [&](int cur, int t0, bool masked) __attribute__((always_inline)) {
            // QK^T from LDS (Q already carries 0.125*log2e)
            f32x4 s[4];
            __builtin_amdgcn_s_setprio(1);
#pragma unroll
            for (int kt = 0; kt < 4; kt++) {
                int r = kt * 16 + c;
                s16x8 kf0 = *(const s16x8*)&Ks[cur][r * 64 + ((g * 8) ^ mR)];
                s16x8 kf1 = *(const s16x8*)&Ks[cur][r * 64 + ((32 + g * 8) ^ mR)];
                f32x4 sv = (f32x4){0, 0, 0, 0};
                sv = __builtin_amdgcn_mfma_f32_16x16x32_bf16(qf0, kf0, sv, 0, 0, 0);
                sv = __builtin_amdgcn_mfma_f32_16x16x32_bf16(qf1, kf1, sv, 0, 0, 0);
                s[kt] = sv;
            }
            __builtin_amdgcn_s_setprio(0);
            // causal mask on diagonal tile only (no scale needed)
            if (masked) {
#pragma unroll
                for (int kt = 0; kt < 4; kt++) {
                    int kcol = t0 + kt * 16 + c;
#pragma unroll
                    for (int j = 0; j < 4; j++) {
                        int qrow = q0 + g * 4 + j;
                        if (kcol > qrow) s[kt][j] = -1e30f;
                    }
                }
            }
            // tile row-max via DPP (16-lane rows)
            float tm4[4];
#pragma unroll
            for (int j = 0; j < 4; j++)
                tm4[j] = dpp_max16(fmaxf(fmaxf(s[0][j], s[1][j]), fmaxf(s[2][j], s[3][j])));
            // defer-max: rescale only if some row's max grew
            bool grow = (tm4[0] > mr[0]) | (tm4[1] > mr[1]) | (tm4[2] > mr[2]) | (tm4[3] > mr[3]);
            if (__any(grow)) {
#pragma unroll
                for (int j = 0; j < 4; j++) {
                    float mnew = fmaxf(mr[j], tm4[j]);
                    float corr = fexp2(mr[j] - mnew);
                    mr[j] = mnew;
                    lr[j] *= corr;
#pragma unroll
                    for (int n = 0; n < 4; n++) acc[n][j] *= corr;
                }
            }
            // P = 2^(s-m), row-sum via DPP
#pragma unroll
            for (int j = 0; j < 4; j++) {
                float p0 = fexp2(s[0][j] - mr[j]);
                float p1 = fexp2(s[1][j] - mr[j]);
                float p2 = fexp2(s[2][j] - mr[j]);
                float p3 = fexp2(s[3][j] - mr[j]);
                s[0][j] = p0; s[1][j] = p1; s[2][j] = p2; s[3][j] = p3;
                lr[j] += dpp_sum16(((p0 + p1) + (p2 + p3)));
            }
            // P -> LDS (bf16 trunc, wave-local, swizzled col ^ ((row&7)<<3))
#pragma unroll
            for (int kt = 0; kt < 4; kt++)
#pragma unroll
                for (int j = 0; j < 4; j++) {
                    int row = g * 4 + j;
                    Plds[wave][row][(kt * 16 + c) ^ ((row & 7) << 3)] = f2bf_trunc(s[kt][j]);
                }
            // PV
            s16x8 pa0 = *(const s16x8*)&Plds[wave][c][(g * 8) ^ pR];
            s16x8 pa1 = *(const s16x8*)&Plds[wave][c][(32 + g * 8) ^ pR];
            __builtin_amdgcn_s_setprio(1);
#pragma unroll
            for (int n = 0; n < 4; n++) {
                int r = n * 16 + c;
                s16x8 vb0 = *(const s16x8*)&Vs[cur][r * 64 + ((g * 8) ^ mR)];
                s16x8 vb1 = *(const s16x8*)&Vs[cur][r * 64 + ((32 + g * 8) ^ mR)];
                acc[n] = __builtin_amdgcn_mfma_f32_16x16x32_bf16(pa0, vb0, acc[n], 0, 0, 0);
                acc[n] = __builtin_amdgcn_mfma_f32_16x16x32_bf16(pa1, vb1, acc[n], 0, 0, 0);
            }
            __builtin_amdgcn_s_setprio(0);
        };

        __syncthreads();              // prev-phase LDS reads done
        stageKV(0, 0);
        __syncthreads();              // prologue staged
        int cur = 0;
        for (int t = 0; t < qt; t++) {                 // strictly-below-diagonal tiles
            stageKV(cur ^ 1, (t + 1) * 64);            // prefetch next tile
            do_tile(cur, t * 64, false);
            __syncthreads();
            cur ^= 1;
        }
        do_tile(cur, qt * 64, true);                   // diagonal tile (masked)

        // epilogue: normalize and store bf16
#pragma unroll
        for (int j = 0; j < 4; j++) {
            float inv = 1.f / lr[j];
            size_t rbase = (size_t)(b * S + q0 + g * 4 + j) * 1024 + h * 64;
#pragma unroll
            for (int n = 0; n < 4; n++)
                o[rbase + n * 16 + c] = f2bf(acc[n][j] * inv);
        }
    }
}

// ---------- host ----------
extern "C" void kernel_launch(void* const* d_in, const int* in_sizes, int n_in,
                              void* d_out, int out_size, void* d_ws, size_t ws_size,
                              hipStream_t stream)
{
    const float* x    = (const float*)d_in[0];
    const float* Wq   = (const float*)d_in[2];  const float* bq = (const float*)d_in[3];
    const float* Wk   = (const float*)d_in[4];  const float* bk = (const float*)d_in[5];
    const float* Wv   = (const float*)d_in[6];  const float* bv = (const float*)d_in[7];
    const float* Wo   = (const float*)d_in[8];  const float* bo = (const float*)d_in[9];
    const float* W1   = (const float*)d_in[10]; const float* b1 = (const float*)d_in[11];
    const float* W2   = (const float*)d_in[12]; const float* b2 = (const float*)d_in[13];
    const float* ln1g = (const float*)d_in[14]; const float* ln1b = (const float*)d_in[15];
    const float* ln2g = (const float*)d_in[16]; const float* ln2b = (const float*)d_in[17];

    unsigned char* ws = (unsigned char*)d_ws;
    u16*   Wqkv_t = (u16*)(ws + 0);              //  6,291,456  bf16 [3072][1024]
    u16*   Wo_t   = (u16*)(ws + 6291456);        //  2,097,152  bf16 [1024][1024]
    u16*   W1_t   = (u16*)(ws + 8388608);        //  8,388,608  bf16 [4096][1024]
    u16*   W2_t   = (u16*)(ws + 16777216);       //  8,388,608  bf16 [1024][4096]
    float* bqkv   = (float*)(ws + 25165824);     //     12,288  f32  [3072]
    u16*   lnbuf  = (u16*)(ws + 25178112);       //  8,388,608  bf16
    u16*   qkvbuf = (u16*)(ws + 33566720);       // 25,165,824  bf16 [4096][3072]
    u16*   attnb  = (u16*)(ws + 58732544);       //  8,388,608  bf16 [4096][1024]
    u16*   f1buf  = (u16*)(ws + 33566720);       // 33,554,432  bf16 [4096][4096] (aliases qkv+attn)
    float* hbuf   = (float*)(ws + 67121152);     // 16,777,216  f32  [4096][1024]
    u16*   vtbuf  = (u16*)(ws + 67121152);       //  8,388,608  bf16 [32][64][2048] (aliases hbuf)

    transpose_all<<<12300, 256, 0, stream>>>(Wq, Wk, Wv, Wo, W1, W2, bq, bk, bv,
                                             Wqkv_t, Wo_t, W1_t, W2_t, bqkv);

    // ln1 -> fused QKV GEMM (Q cols pre-scaled) -> V transpose -> attention
    ln_k<<<1024, 256, 0, stream>>>(x, ln1g, ln1b, lnbuf);
    gemm2<128, 0, false, false, 1><<<dim3(24, 32), 256, 0, stream>>>(
        lnbuf, Wqkv_t, bqkv, nullptr, qkvbuf, 4096, 3072, 1024);
    v_transpose<<<dim3(32, 32), 256, 0, stream>>>(qkvbuf, vtbuf);
    attn_fwd6<<<dim3(16, 32), 256, 0, stream>>>(qkvbuf, vtbuf, attnb);

    // h = x + attn @ Wo + bo  (f32)
    gemm_n64_k64<<<dim3(16, 32), 256, 0, stream>>>(
        attnb, Wo_t, bo, x, hbuf, 4096, 1024, 1024);

    // ln2 -> FFN1 (relu) -> FFN2 (+h residual) -> out (f32)
    ln_k<<<1024, 256, 0, stream>>>(hbuf, ln2g, ln2b, lnbuf);
    gemm2<128, 0, true, false><<<dim3(32, 32), 256, 0, stream>>>(
        lnbuf, W1_t, b1, nullptr, f1buf, 4096, 4096, 1024);
    gemm_n64_k64<<<dim3(16, 32), 256, 0, stream>>>(
        f1buf, W2_t, b2, hbuf, (float*)d_out, 4096, 1024, 4096);
}